// Round 2
// baseline (638.015 us; speedup 1.0000x reference)
//
#include <hip/hip_runtime.h>
#include <hip/hip_bf16.h>

#define BDIM 1024
#define EDIM 512
#define CDIM 70722
#define SCALE 64.0f
#define EPS_C 1e-3f
#define M_COEF 0.4f
#define H_COEF 0.333f
#define PI_F 3.14159265358979323846f

using short8 = __attribute__((ext_vector_type(8))) short;
using f32x4  = __attribute__((ext_vector_type(4))) float;

__device__ __forceinline__ unsigned short f2bf(float f) {
    union { float f; unsigned int u; } x; x.f = f;
    unsigned int u = x.u;
    unsigned int r = (u + 0x7fffu + ((u >> 16) & 1u)) >> 16;   // RTNE
    return (unsigned short)r;
}

// ---------------------------------------------------------------------------
// Kernel 1: embeddings f32 -> bf16 (row-major M x K). 2 MB read, 1 MB write.
// ---------------------------------------------------------------------------
__global__ __launch_bounds__(256) void convert_A(
        const float* __restrict__ emb, unsigned short* __restrict__ Abf) {
    int i = (blockIdx.x * 256 + threadIdx.x) * 4;
    float4 v = *(const float4*)&emb[i];
    ushort4 o;
    o.x = f2bf(v.x); o.y = f2bf(v.y); o.z = f2bf(v.z); o.w = f2bf(v.w);
    *(ushort4*)&Abf[i] = o;
}

// ---------------------------------------------------------------------------
// Kernel 2: FUSED  column-norm + bf16 convert + GEMM + epilogue.
// 128x128 tile, BK=32, 4 waves (2x2). B staged straight from f32 Kw (k-major)
// via regs -> padded f32 LDS tile -> transposed bf16 Bs. Column sumsq kept in
// registers (each thread owns 4 fixed columns across all K), reduced at end.
// As/Bs use slot XOR swizzle: slot = row*4 + (khat ^ ((row>>1)&3)); applied to
// the GLOBAL source address for A's global_load_lds (linear LDS dest).
// XCD swizzle: the 8 m-blocks of one n-strip run consecutively on one XCD.
// ---------------------------------------------------------------------------
__global__ __launch_bounds__(256) void gemm_fused(
        const unsigned short* __restrict__ A,   // 1024 x 512 bf16
        const float* __restrict__ Kw,           // 512 x 70722 f32
        float* __restrict__ out) {
    __shared__ unsigned short As[128 * 32];
    __shared__ unsigned short Bs[128 * 32];
    __shared__ float Tf[32 * 132];              // f32 transpose tile; reused for reduce

    // --- block swizzle: 553 n-strips x 8 m-strips; 552 strips grouped 8-per-XCD ---
    const int bid = blockIdx.x;
    int m_blk, n_blk;
    if (bid < 4416) {
        const int x = bid & 7;          // XCD (round-robin dispatch)
        const int j = bid >> 3;         // sequence within XCD, m varies fastest
        n_blk = ((j >> 3) << 3) + x;
        m_blk = j & 7;
    } else {
        n_blk = 552;
        m_blk = bid - 4416;
    }
    const int m0 = m_blk << 7;
    const int n0 = n_blk << 7;

    const int tid  = threadIdx.x;
    const int w    = tid >> 6;
    const int lane = tid & 63;
    const int wm   = w >> 1;
    const int wn   = w & 1;
    const int lrow = lane & 15;
    const int khf  = lane >> 4;          // fragment k-slot 0..3
    const int gsw  = (lrow >> 1) & 3;    // read-side XOR swizzle term

    f32x4 acc[4][4] = {};
    float ssq0 = 0.f, ssq1 = 0.f, ssq2 = 0.f, ssq3 = 0.f;

    // B-load geometry (fixed columns per thread across the whole K loop)
    const int bl_c = (tid & 31) << 2;    // local col 0..124
    const int bl_r = tid >> 5;           // k-row group 0..7
    const float* bptr = Kw + (size_t)bl_r * CDIM + n0 + bl_c;
    const bool edge = (n_blk == 552);
    const int  crem = CDIM - n0;         // 128 normally, 66 on the edge strip

    for (int kt = 0; kt < 16; ++kt) {
        const int k0 = kt << 5;
        __syncthreads();                 // As/Bs/Tf free for reuse

        // --- B f32 tile (32k x 128n) -> regs, coalesced along n ---
        float4 bv[4];
        const float* bp = bptr + (size_t)k0 * CDIM;
#pragma unroll
        for (int p = 0; p < 4; ++p) {
            const float* rp = bp + (size_t)(p << 3) * CDIM;
            if (!edge) {
                bv[p] = *(const float4*)rp;
            } else {
                float* e = (float*)&bv[p];
                e[0] = (bl_c + 0 < crem) ? rp[0] : 0.f;
                e[1] = (bl_c + 1 < crem) ? rp[1] : 0.f;
                e[2] = (bl_c + 2 < crem) ? rp[2] : 0.f;
                e[3] = (bl_c + 3 < crem) ? rp[3] : 0.f;
            }
        }

        // --- A global->LDS, source pre-swizzled so swizzled reads see right data ---
#pragma unroll
        for (int j = 0; j < 2; ++j) {
            const int sigma = (((j << 2) + w) << 6) + lane;   // 16B slot index
            const int r  = sigma >> 2;
            const int kh = (sigma & 3) ^ ((r >> 1) & 3);
            const unsigned short* ga = A + (size_t)(m0 + r) * EDIM + k0 + (kh << 3);
            __builtin_amdgcn_global_load_lds(
                (const __attribute__((address_space(1))) void*)ga,
                (__attribute__((address_space(3))) void*)((char*)As + (((j << 2) + w) << 10)),
                16, 0, 0);
        }

        // --- spill B regs to padded f32 LDS tile + accumulate column sumsq ---
#pragma unroll
        for (int p = 0; p < 4; ++p) {
            *(float4*)&Tf[(((p << 3) + bl_r) * 132) + bl_c] = bv[p];
            const float* e = (const float*)&bv[p];
            ssq0 += e[0] * e[0]; ssq1 += e[1] * e[1];
            ssq2 += e[2] * e[2]; ssq3 += e[3] * e[3];
        }
        __syncthreads();

        // --- transposed read + convert -> Bs (n-major bf16, XOR-swizzled slots) ---
        const int bn = tid >> 1;             // output row (column index n), 0..127
        const int kb = (tid & 1) << 4;       // 0 or 16
        short8 t0, t1;
#pragma unroll
        for (int jj = 0; jj < 8; ++jj) t0[jj] = (short)f2bf(Tf[(kb + jj) * 132 + bn]);
#pragma unroll
        for (int jj = 0; jj < 8; ++jj) t1[jj] = (short)f2bf(Tf[(kb + 8 + jj) * 132 + bn]);
        const int gswn = (bn >> 1) & 3;
        const int kh0  = (((tid & 1) << 1) + 0) ^ gswn;
        const int kh1  = (((tid & 1) << 1) + 1) ^ gswn;
        *(short8*)((char*)Bs + (((bn << 2) + kh0) << 4)) = t0;
        *(short8*)((char*)Bs + (((bn << 2) + kh1) << 4)) = t1;

        asm volatile("s_waitcnt vmcnt(0)" ::: "memory");   // A's global_load_lds landed
        __syncthreads();

        // --- fragment reads (2-way max after swizzle) + MFMA ---
        short8 af[4], bf[4];
#pragma unroll
        for (int f = 0; f < 4; ++f) {
            const int ar = (wm << 6) + (f << 4) + lrow;
            af[f] = *(const short8*)((const char*)As + (((ar << 2) + (khf ^ gsw)) << 4));
            const int br = (wn << 6) + (f << 4) + lrow;
            bf[f] = *(const short8*)((const char*)Bs + (((br << 2) + (khf ^ gsw)) << 4));
        }
#pragma unroll
        for (int i = 0; i < 4; ++i)
#pragma unroll
            for (int jj = 0; jj < 4; ++jj)
                acc[i][jj] = __builtin_amdgcn_mfma_f32_16x16x32_bf16(
                    af[i], bf[jj], acc[i][jj], 0, 0, 0);
    }

    // --- column inv-norm: 8-way cross-thread reduce of register sumsq ---
    __syncthreads();
    float* sred = Tf;                       // reuse: 1024 partials + 128 inv norms
    const int sbase = (bl_r << 7) + bl_c;
    sred[sbase + 0] = ssq0; sred[sbase + 1] = ssq1;
    sred[sbase + 2] = ssq2; sred[sbase + 3] = ssq3;
    __syncthreads();
    if (tid < 128) {
        float s = 0.f;
#pragma unroll
        for (int r = 0; r < 8; ++r) s += sred[(r << 7) + tid];
        sred[1024 + tid] = rsqrtf(s);
    }
    __syncthreads();

    // --- epilogue: cosine = acc * invnorm, clip, *SCALE ---
    const int colLoc  = (wn << 6) + lrow;
    const int rowBase = m0 + (wm << 6) + (khf << 2);
#pragma unroll
    for (int jj = 0; jj < 4; ++jj) {
        const int cl = colLoc + (jj << 4);
        const int cg = n0 + cl;
        if (cg < CDIM) {
            const float invn = sred[1024 + cl];
#pragma unroll
            for (int i = 0; i < 4; ++i) {
#pragma unroll
                for (int r = 0; r < 4; ++r) {
                    const int rg = rowBase + (i << 4) + r;
                    float v = acc[i][jj][r] * invn;
                    v = fminf(fmaxf(v, -1.0f + EPS_C), 1.0f - EPS_C);
                    out[(size_t)rg * CDIM + cg] = v * SCALE;
                }
            }
        }
    }
}

// ---------------------------------------------------------------------------
// Kernel 3: margin fixup on the label column of each row.
// ---------------------------------------------------------------------------
__global__ __launch_bounds__(1024) void fixup_kernel(
        const float* __restrict__ norms, const int* __restrict__ label,
        float* __restrict__ out) {
    __shared__ float red[1024];
    const int t = threadIdx.x;
    const float x = fminf(fmaxf(norms[t], 1e-3f), 100.0f);

    red[t] = x;
    __syncthreads();
#pragma unroll
    for (int s = 512; s > 0; s >>= 1) {
        if (t < s) red[t] += red[t + s];
        __syncthreads();
    }
    const float mean = red[0] * (1.0f / 1024.0f);
    __syncthreads();

    const float d = x - mean;
    red[t] = d * d;
    __syncthreads();
#pragma unroll
    for (int s = 512; s > 0; s >>= 1) {
        if (t < s) red[t] += red[t + s];
        __syncthreads();
    }
    const float stdv = sqrtf(red[0] * (1.0f / 1023.0f));   // ddof=1

    float ms = (x - mean) / (stdv + EPS_C) * H_COEF;
    ms = fminf(fmaxf(ms, -1.0f), 1.0f);
    const float g_ang = -M_COEF * ms;
    const float g_add = M_COEF + M_COEF * ms;

    const size_t idx = (size_t)t * CDIM + label[t];
    const float c = out[idx] * (1.0f / SCALE);
    float theta = acosf(c) + g_ang;
    theta = fminf(fmaxf(theta, EPS_C), PI_F - EPS_C);
    out[idx] = (cosf(theta) - g_add) * SCALE;
}

// ---------------------------------------------------------------------------
extern "C" void kernel_launch(void* const* d_in, const int* in_sizes, int n_in,
                              void* d_out, int out_size, void* d_ws, size_t ws_size,
                              hipStream_t stream) {
    const float* emb   = (const float*)d_in[0];
    const float* norms = (const float*)d_in[1];
    const int*   label = (const int*)d_in[2];
    const float* Kw    = (const float*)d_in[3];
    float* out = (float*)d_out;

    unsigned short* Abf = (unsigned short*)d_ws;   // 1 MB scratch

    convert_A<<<dim3(BDIM * EDIM / (256 * 4)), 256, 0, stream>>>(emb, Abf);
    gemm_fused<<<dim3(553 * 8), 256, 0, stream>>>(Abf, Kw, out);
    fixup_kernel<<<1, 1024, 0, stream>>>(norms, label, out);
}